// Round 7
// baseline (210.923 us; speedup 1.0000x reference)
//
#include <hip/hip_runtime.h>

typedef __attribute__((ext_vector_type(8))) short short8;
typedef __attribute__((ext_vector_type(4))) float f32x4;

#define BATCH 32
#define LSEQ  512
#define DIN   256
#define FDIM  256
#define MT    32             // conv output rows per block
#define BK    32             // K-chunk
#define PADA  264            // 256 + 8 shorts row stride for LDS tiles

__device__ __forceinline__ short f2bf(float f) {
    union { float f; unsigned u; } v; v.f = f;
    unsigned r = v.u + 0x7FFFu + ((v.u >> 16) & 1u);   // RNE
    return (short)(r >> 16);
}

// ---------------- prep: per-batch scan -> frame index table (blocks 0..31) + weight repack ----------------
__global__ __launch_bounds__(512)
void prep_kernel(const int* __restrict__ dur, int* __restrict__ fidx, int M,
                 const float* __restrict__ w1, const float* __restrict__ w2,
                 short* __restrict__ wt1, short* __restrict__ wt2) {
    __shared__ int s[LSEQ];
    const int t = threadIdx.x, b = blockIdx.x;
    if (b < BATCH) {
        s[t] = dur[b * LSEQ + t];
        __syncthreads();
        for (int off = 1; off < LSEQ; off <<= 1) {
            int v = (t >= off) ? s[t - off] : 0;
            __syncthreads();
            s[t] += v;
            __syncthreads();
        }
        for (int f = t; f < M; f += 512) fidx[b * M + f] = -1;
        __syncthreads();
        int lo = (t == 0) ? 0 : s[t - 1];
        int hi = s[t];
        if (hi > M) hi = M;
        for (int j = lo; j < hi; j++) fidx[b * M + j] = b * LSEQ + t;
    } else {
        const int id = (b - BATCH) * 512 + t;          // coalesced read
        const int n = id & 255, k = id >> 8;
        const int dst = (((k >> 5) * FDIM) + n) * BK + (k & 31);
        wt1[dst] = f2bf(w1[id]);
        wt2[dst] = f2bf(w2[id]);
    }
}

// ------------- fused duration predictor: conv1+LN1+ReLU -> conv2+LN2+ReLU -> linear -------------
// Block: 256 thr = 4 waves, 32 output rows, full 256 cols (64/wave).
// Stage x rows r0-2..r0+33 (36) once; conv1 produces h1 rows r0-1..r0+32 (34)
// in-register (2 full m-tiles + 1 partial), LN1 -> bf16 tile in LDS (batch-edge
// rows zeroed for 'same' padding), conv2 reads it; both K-loops barrier-free.
__global__ __launch_bounds__(256)
void fused_dp(const float* __restrict__ x,
              const short* __restrict__ Bt1, const short* __restrict__ Bt2,
              const float* __restrict__ c1b, const float* __restrict__ g1v,
              const float* __restrict__ b1v,
              const float* __restrict__ c2b, const float* __restrict__ g2v,
              const float* __restrict__ b2v,
              const float* __restrict__ lw, const float* __restrict__ lb,
              float* __restrict__ Dout)
{
    __shared__ short As[36][PADA];      // x tile, bf16   (~19.0 KB)
    __shared__ short Hs[34][PADA];      // h1 tile, bf16  (~18.0 KB)
    __shared__ float redS[34][4];
    __shared__ float redQ[34][4];
    __shared__ float redD[MT][4];
    __shared__ float muS[34];
    __shared__ float rsS[34];

    const int tid  = threadIdx.x;
    const int wave = tid >> 6;
    const int lane = tid & 63;
    const int ml   = lane & 15;
    const int q    = lane >> 4;
    const int row0 = blockIdx.x * MT;
    const int bb   = row0 >> 9;          // batch
    const int r0b  = row0 & (LSEQ - 1);  // row within batch

    // ---- stage x rows [r0-2 .. r0+33] (zeros outside batch) ----
    for (int idx = tid; idx < 36 * 32; idx += 256) {
        const int r = idx >> 5, part = idx & 31;
        const int l2 = r0b + r - 2;
        short8 v = {0, 0, 0, 0, 0, 0, 0, 0};
        if (l2 >= 0 && l2 < LSEQ) {
            const f32x4* s4 = (const f32x4*)(x + ((size_t)(bb * LSEQ + l2)) * DIN + part * 8);
            f32x4 u0 = s4[0], u1 = s4[1];
            v[0] = f2bf(u0.x); v[1] = f2bf(u0.y); v[2] = f2bf(u0.z); v[3] = f2bf(u0.w);
            v[4] = f2bf(u1.x); v[5] = f2bf(u1.y); v[6] = f2bf(u1.z); v[7] = f2bf(u1.w);
        }
        *(short8*)&As[r][part * 8] = v;
    }
    __syncthreads();

    // ================= conv1: h1 rows m = 0..33 (h row = r0-1+m) =================
    f32x4 acc[2][4];     // full tiles: rows 0..31
    f32x4 acce[4];       // partial tile: rows 32..33 valid
    #pragma unroll
    for (int mt = 0; mt < 2; mt++)
        #pragma unroll
        for (int nt = 0; nt < 4; nt++)
            #pragma unroll
            for (int r = 0; r < 4; r++)
                acc[mt][nt][r] = 0.f;
    #pragma unroll
    for (int nt = 0; nt < 4; nt++)
        #pragma unroll
        for (int r = 0; r < 4; r++)
            acce[nt][r] = 0.f;

    {
        const short* bptr = Bt1 + (size_t)(wave * 64 + ml) * BK + q * 8;
        #pragma unroll 1
        for (int tap = 0; tap < 3; tap++) {
            int are = 32 + ml + tap; if (are > 35) are = 35;   // clamp; rows>1 of partial tile discarded
            #pragma unroll
            for (int cc = 0; cc < 8; cc++) {
                short8 af0 = *(const short8*)&As[ 0 + ml + tap][cc * 32 + q * 8];
                short8 af1 = *(const short8*)&As[16 + ml + tap][cc * 32 + q * 8];
                short8 af2 = *(const short8*)&As[are][cc * 32 + q * 8];
                short8 b0 = *(const short8*)(bptr + 0 * 16 * BK);
                short8 b1 = *(const short8*)(bptr + 1 * 16 * BK);
                short8 b2 = *(const short8*)(bptr + 2 * 16 * BK);
                short8 b3 = *(const short8*)(bptr + 3 * 16 * BK);
                bptr += FDIM * BK;
                acc[0][0] = __builtin_amdgcn_mfma_f32_16x16x32_bf16(af0, b0, acc[0][0], 0, 0, 0);
                acc[0][1] = __builtin_amdgcn_mfma_f32_16x16x32_bf16(af0, b1, acc[0][1], 0, 0, 0);
                acc[0][2] = __builtin_amdgcn_mfma_f32_16x16x32_bf16(af0, b2, acc[0][2], 0, 0, 0);
                acc[0][3] = __builtin_amdgcn_mfma_f32_16x16x32_bf16(af0, b3, acc[0][3], 0, 0, 0);
                acc[1][0] = __builtin_amdgcn_mfma_f32_16x16x32_bf16(af1, b0, acc[1][0], 0, 0, 0);
                acc[1][1] = __builtin_amdgcn_mfma_f32_16x16x32_bf16(af1, b1, acc[1][1], 0, 0, 0);
                acc[1][2] = __builtin_amdgcn_mfma_f32_16x16x32_bf16(af1, b2, acc[1][2], 0, 0, 0);
                acc[1][3] = __builtin_amdgcn_mfma_f32_16x16x32_bf16(af1, b3, acc[1][3], 0, 0, 0);
                acce[0]   = __builtin_amdgcn_mfma_f32_16x16x32_bf16(af2, b0, acce[0], 0, 0, 0);
                acce[1]   = __builtin_amdgcn_mfma_f32_16x16x32_bf16(af2, b1, acce[1], 0, 0, 0);
                acce[2]   = __builtin_amdgcn_mfma_f32_16x16x32_bf16(af2, b2, acce[2], 0, 0, 0);
                acce[3]   = __builtin_amdgcn_mfma_f32_16x16x32_bf16(af2, b3, acce[3], 0, 0, 0);
            }
        }
    }

    // ---- bias + LN1 reduction over 34 rows ----
    float cbv[4], gv[4], bv[4];
    #pragma unroll
    for (int nt = 0; nt < 4; nt++) {
        const int col = wave * 64 + nt * 16 + ml;
        cbv[nt] = c1b[col]; gv[nt] = g1v[col]; bv[nt] = b1v[col];
    }
    #pragma unroll
    for (int mt = 0; mt < 2; mt++)
        #pragma unroll
        for (int nt = 0; nt < 4; nt++)
            #pragma unroll
            for (int r = 0; r < 4; r++)
                acc[mt][nt][r] += cbv[nt];
    #pragma unroll
    for (int nt = 0; nt < 4; nt++)
        #pragma unroll
        for (int r = 0; r < 4; r++)
            acce[nt][r] += cbv[nt];

    #pragma unroll
    for (int mt = 0; mt < 2; mt++)
        #pragma unroll
        for (int r = 0; r < 4; r++) {
            float ps = 0.f, pq = 0.f;
            #pragma unroll
            for (int nt = 0; nt < 4; nt++) { float v = acc[mt][nt][r]; ps += v; pq += v * v; }
            #pragma unroll
            for (int d = 1; d < 16; d <<= 1) { ps += __shfl_xor(ps, d); pq += __shfl_xor(pq, d); }
            if (ml == 0) { const int row = mt * 16 + q * 4 + r; redS[row][wave] = ps; redQ[row][wave] = pq; }
        }
    #pragma unroll
    for (int r = 0; r < 2; r++) {          // partial tile rows 32,33 (q==0)
        float ps = 0.f, pq = 0.f;
        #pragma unroll
        for (int nt = 0; nt < 4; nt++) { float v = acce[nt][r]; ps += v; pq += v * v; }
        #pragma unroll
        for (int d = 1; d < 16; d <<= 1) { ps += __shfl_xor(ps, d); pq += __shfl_xor(pq, d); }
        if (ml == 0 && q == 0) { redS[32 + r][wave] = ps; redQ[32 + r][wave] = pq; }
    }
    __syncthreads();
    if (tid < 34) {
        float S = 0.f, Q = 0.f;
        #pragma unroll
        for (int w = 0; w < 4; w++) { S += redS[tid][w]; Q += redQ[tid][w]; }
        const float mu  = S * (1.f / 256.f);
        const float var = Q * (1.f / 256.f) - mu * mu;
        muS[tid] = mu; rsS[tid] = rsqrtf(var + 1e-5f);
    }
    __syncthreads();

    // ---- apply LN1+ReLU, write bf16 h1 tile (zero outside-batch rows) ----
    #pragma unroll
    for (int mt = 0; mt < 2; mt++)
        #pragma unroll
        for (int r = 0; r < 4; r++) {
            const int row = mt * 16 + q * 4 + r;
            const bool ok = (unsigned)(r0b - 1 + row) < (unsigned)LSEQ;
            const float mu = muS[row], rs = rsS[row];
            #pragma unroll
            for (int nt = 0; nt < 4; nt++) {
                const int col = wave * 64 + nt * 16 + ml;
                float v = (acc[mt][nt][r] - mu) * rs * gv[nt] + bv[nt];
                v = ok ? fmaxf(v, 0.f) : 0.f;
                Hs[row][col] = f2bf(v);
            }
        }
    if (q == 0) {
        #pragma unroll
        for (int r = 0; r < 2; r++) {
            const int row = 32 + r;
            const bool ok = (unsigned)(r0b - 1 + row) < (unsigned)LSEQ;
            const float mu = muS[row], rs = rsS[row];
            #pragma unroll
            for (int nt = 0; nt < 4; nt++) {
                const int col = wave * 64 + nt * 16 + ml;
                float v = (acce[nt][r] - mu) * rs * gv[nt] + bv[nt];
                v = ok ? fmaxf(v, 0.f) : 0.f;
                Hs[row][col] = f2bf(v);
            }
        }
    }
    __syncthreads();

    // ================= conv2: output rows 0..31 from Hs =================
    f32x4 acc2[2][4];
    #pragma unroll
    for (int mt = 0; mt < 2; mt++)
        #pragma unroll
        for (int nt = 0; nt < 4; nt++)
            #pragma unroll
            for (int r = 0; r < 4; r++)
                acc2[mt][nt][r] = 0.f;
    {
        const short* bptr = Bt2 + (size_t)(wave * 64 + ml) * BK + q * 8;
        #pragma unroll 1
        for (int tap = 0; tap < 3; tap++) {
            #pragma unroll
            for (int cc = 0; cc < 8; cc++) {
                short8 af0 = *(const short8*)&Hs[ 0 + ml + tap][cc * 32 + q * 8];
                short8 af1 = *(const short8*)&Hs[16 + ml + tap][cc * 32 + q * 8];
                short8 b0 = *(const short8*)(bptr + 0 * 16 * BK);
                short8 b1 = *(const short8*)(bptr + 1 * 16 * BK);
                short8 b2 = *(const short8*)(bptr + 2 * 16 * BK);
                short8 b3 = *(const short8*)(bptr + 3 * 16 * BK);
                bptr += FDIM * BK;
                acc2[0][0] = __builtin_amdgcn_mfma_f32_16x16x32_bf16(af0, b0, acc2[0][0], 0, 0, 0);
                acc2[0][1] = __builtin_amdgcn_mfma_f32_16x16x32_bf16(af0, b1, acc2[0][1], 0, 0, 0);
                acc2[0][2] = __builtin_amdgcn_mfma_f32_16x16x32_bf16(af0, b2, acc2[0][2], 0, 0, 0);
                acc2[0][3] = __builtin_amdgcn_mfma_f32_16x16x32_bf16(af0, b3, acc2[0][3], 0, 0, 0);
                acc2[1][0] = __builtin_amdgcn_mfma_f32_16x16x32_bf16(af1, b0, acc2[1][0], 0, 0, 0);
                acc2[1][1] = __builtin_amdgcn_mfma_f32_16x16x32_bf16(af1, b1, acc2[1][1], 0, 0, 0);
                acc2[1][2] = __builtin_amdgcn_mfma_f32_16x16x32_bf16(af1, b2, acc2[1][2], 0, 0, 0);
                acc2[1][3] = __builtin_amdgcn_mfma_f32_16x16x32_bf16(af1, b3, acc2[1][3], 0, 0, 0);
            }
        }
    }

    // ---- bias + LN2 + ReLU + fused linear ----
    float lwv[4];
    #pragma unroll
    for (int nt = 0; nt < 4; nt++) {
        const int col = wave * 64 + nt * 16 + ml;
        cbv[nt] = c2b[col]; gv[nt] = g2v[col]; bv[nt] = b2v[col]; lwv[nt] = lw[col];
    }
    #pragma unroll
    for (int mt = 0; mt < 2; mt++)
        #pragma unroll
        for (int nt = 0; nt < 4; nt++)
            #pragma unroll
            for (int r = 0; r < 4; r++)
                acc2[mt][nt][r] += cbv[nt];

    #pragma unroll
    for (int mt = 0; mt < 2; mt++)
        #pragma unroll
        for (int r = 0; r < 4; r++) {
            float ps = 0.f, pq = 0.f;
            #pragma unroll
            for (int nt = 0; nt < 4; nt++) { float v = acc2[mt][nt][r]; ps += v; pq += v * v; }
            #pragma unroll
            for (int d = 1; d < 16; d <<= 1) { ps += __shfl_xor(ps, d); pq += __shfl_xor(pq, d); }
            if (ml == 0) { const int row = mt * 16 + q * 4 + r; redS[row][wave] = ps; redQ[row][wave] = pq; }
        }
    __syncthreads();
    if (tid < MT) {
        float S = 0.f, Q = 0.f;
        #pragma unroll
        for (int w = 0; w < 4; w++) { S += redS[tid][w]; Q += redQ[tid][w]; }
        const float mu  = S * (1.f / 256.f);
        const float var = Q * (1.f / 256.f) - mu * mu;
        muS[tid] = mu; rsS[tid] = rsqrtf(var + 1e-5f);
    }
    __syncthreads();

    #pragma unroll
    for (int mt = 0; mt < 2; mt++)
        #pragma unroll
        for (int r = 0; r < 4; r++) {
            const int row = mt * 16 + q * 4 + r;
            const float mu = muS[row], rs = rsS[row];
            float pd = 0.f;
            #pragma unroll
            for (int nt = 0; nt < 4; nt++) {
                float v = (acc2[mt][nt][r] - mu) * rs * gv[nt] + bv[nt];
                v = fmaxf(v, 0.f);
                pd += v * lwv[nt];
            }
            #pragma unroll
            for (int d = 1; d < 16; d <<= 1) pd += __shfl_xor(pd, d);
            if (ml == 0) redD[row][wave] = pd;
        }
    __syncthreads();
    if (tid < MT) {
        float Dv = 0.f;
        #pragma unroll
        for (int w = 0; w < 4; w++) Dv += redD[tid][w];
        Dout[row0 + tid] = fmaxf(Dv + lb[0], 0.f);
    }
}

// ---------------- expand: 16 frames per block, 4 independent chains per wave, NT stores ----------------
__global__ __launch_bounds__(256)
void expand_kernel(const f32x4* __restrict__ x4, const int* __restrict__ fidx,
                   f32x4* __restrict__ out4) {
    const int wave = threadIdx.x >> 6;
    const int lane = threadIdx.x & 63;
    const int fr0  = blockIdx.x * 16 + wave * 4;

    int idx[4];
    #pragma unroll
    for (int j = 0; j < 4; j++) idx[j] = fidx[fr0 + j];   // wave-broadcast loads

    f32x4 v[4];
    #pragma unroll
    for (int j = 0; j < 4; j++) {
        v[j] = (f32x4){0.f, 0.f, 0.f, 0.f};
        if (idx[j] >= 0) v[j] = x4[(size_t)idx[j] * 64 + lane];   // 4 independent 1KB gathers
    }
    #pragma unroll
    for (int j = 0; j < 4; j++)
        __builtin_nontemporal_store(v[j], &out4[(size_t)(fr0 + j) * 64 + lane]);
}

extern "C" void kernel_launch(void* const* d_in, const int* in_sizes, int n_in,
                              void* d_out, int out_size, void* d_ws, size_t ws_size,
                              hipStream_t stream)
{
    const float* x   = (const float*)d_in[0];
    const int*   dur = (const int*)d_in[1];
    const float* c1w = (const float*)d_in[3];
    const float* c1b = (const float*)d_in[4];
    const float* g1  = (const float*)d_in[5];
    const float* b1  = (const float*)d_in[6];
    const float* c2w = (const float*)d_in[7];
    const float* c2b = (const float*)d_in[8];
    const float* g2  = (const float*)d_in[9];
    const float* b2  = (const float*)d_in[10];
    const float* lw  = (const float*)d_in[11];
    const float* lb  = (const float*)d_in[12];

    const int M = (out_size - BATCH * LSEQ) / (BATCH * DIN);   // 4096
    float* out     = (float*)d_out;
    float* dur_out = out + (size_t)BATCH * M * DIN;

    char* ws   = (char*)d_ws;
    int*  fidx = (int*)ws;                                      // 512 KB
    short* wt1 = (short*)(ws + (512 << 10));                    // 384 KB
    short* wt2 = (short*)(ws + (512 << 10) + (384 << 10));      // 384 KB

    hipLaunchKernelGGL(prep_kernel, dim3(BATCH + (3 * DIN * FDIM) / 512), dim3(512), 0, stream,
                       dur, fidx, M, c1w, c2w, wt1, wt2);
    hipLaunchKernelGGL(fused_dp, dim3((BATCH * LSEQ) / MT), dim3(256), 0, stream,
                       x, wt1, wt2, c1b, g1, b1, c2b, g2, b2, lw, lb, dur_out);
    hipLaunchKernelGGL(expand_kernel, dim3((BATCH * M) / 16), dim3(256), 0, stream,
                       (const f32x4*)x, fidx, (f32x4*)d_out);
}

// Round 8
// 194.703 us; speedup vs baseline: 1.0833x; 1.0833x over previous
//
#include <hip/hip_runtime.h>

typedef __attribute__((ext_vector_type(8))) short short8;
typedef __attribute__((ext_vector_type(4))) float f32x4;

#define BATCH 32
#define LSEQ  512
#define DIN   256
#define FDIM  256
#define MT    32             // conv output rows per block
#define BK    32             // K-chunk
#define PADA  264            // 256 + 8 shorts row stride for LDS tiles

__device__ __forceinline__ short f2bf(float f) {
    union { float f; unsigned u; } v; v.f = f;
    unsigned r = v.u + 0x7FFFu + ((v.u >> 16) & 1u);   // RNE
    return (short)(r >> 16);
}

// ---------------- prep: per-batch scan -> frame index table (blocks 0..31) + weight repack ----------------
__global__ __launch_bounds__(512)
void prep_kernel(const int* __restrict__ dur, int* __restrict__ fidx, int M,
                 const float* __restrict__ w1, const float* __restrict__ w2,
                 short* __restrict__ wt1, short* __restrict__ wt2) {
    __shared__ int s[LSEQ];
    const int t = threadIdx.x, b = blockIdx.x;
    if (b < BATCH) {
        s[t] = dur[b * LSEQ + t];
        __syncthreads();
        for (int off = 1; off < LSEQ; off <<= 1) {
            int v = (t >= off) ? s[t - off] : 0;
            __syncthreads();
            s[t] += v;
            __syncthreads();
        }
        for (int f = t; f < M; f += 512) fidx[b * M + f] = -1;
        __syncthreads();
        int lo = (t == 0) ? 0 : s[t - 1];
        int hi = s[t];
        if (hi > M) hi = M;
        for (int j = lo; j < hi; j++) fidx[b * M + j] = b * LSEQ + t;
    } else {
        const int id = (b - BATCH) * 512 + t;          // coalesced read
        const int n = id & 255, k = id >> 8;
        const int dst = (((k >> 5) * FDIM) + n) * BK + (k & 31);
        wt1[dst] = f2bf(w1[id]);
        wt2[dst] = f2bf(w2[id]);
    }
}

// ------------- mega kernel: fused duration predictor (blocks 0..nconv-1) + expand (rest) -------------
// Conv path: conv1+LN1+ReLU -> conv2+LN2+ReLU -> linear, per R7's fused_dp.
// Expand path: 16 frames/block, 4 independent 1KB gather->NT-store chains per wave.
// Conv blocks FIRST so the compute-bound work starts immediately; expand blocks
// backfill freed CU slots -> memory/compute overlap within one dispatch.
__global__ __launch_bounds__(256)
void mega_kernel(const float* __restrict__ x,
                 const short* __restrict__ Bt1, const short* __restrict__ Bt2,
                 const float* __restrict__ c1b, const float* __restrict__ g1v,
                 const float* __restrict__ b1v,
                 const float* __restrict__ c2b, const float* __restrict__ g2v,
                 const float* __restrict__ b2v,
                 const float* __restrict__ lw, const float* __restrict__ lb,
                 float* __restrict__ Dout,
                 const f32x4* __restrict__ x4, const int* __restrict__ fidx,
                 f32x4* __restrict__ out4, int nconv)
{
    __shared__ short As[36][PADA];      // x tile, bf16   (~19.0 KB)
    __shared__ short Hs[34][PADA];      // h1 tile, bf16  (~18.0 KB)
    __shared__ float redS[34][4];
    __shared__ float redQ[34][4];
    __shared__ float redD[MT][4];
    __shared__ float muS[34];
    __shared__ float rsS[34];

    const int tid  = threadIdx.x;
    const int wave = tid >> 6;
    const int lane = tid & 63;

    if ((int)blockIdx.x >= nconv) {
        // ---------------- expand path ----------------
        const int fr0 = ((int)blockIdx.x - nconv) * 16 + wave * 4;
        int idx[4];
        #pragma unroll
        for (int j = 0; j < 4; j++) idx[j] = fidx[fr0 + j];   // wave-broadcast loads
        f32x4 v[4];
        #pragma unroll
        for (int j = 0; j < 4; j++) {
            v[j] = (f32x4){0.f, 0.f, 0.f, 0.f};
            if (idx[j] >= 0) v[j] = x4[(size_t)idx[j] * 64 + lane];   // 4 independent 1KB gathers
        }
        #pragma unroll
        for (int j = 0; j < 4; j++)
            __builtin_nontemporal_store(v[j], &out4[(size_t)(fr0 + j) * 64 + lane]);
        return;
    }

    // ---------------- conv path ----------------
    const int ml   = lane & 15;
    const int q    = lane >> 4;
    const int row0 = blockIdx.x * MT;
    const int bb   = row0 >> 9;          // batch
    const int r0b  = row0 & (LSEQ - 1);  // row within batch

    // ---- stage x rows [r0-2 .. r0+33] (zeros outside batch) ----
    for (int idx = tid; idx < 36 * 32; idx += 256) {
        const int r = idx >> 5, part = idx & 31;
        const int l2 = r0b + r - 2;
        short8 v = {0, 0, 0, 0, 0, 0, 0, 0};
        if (l2 >= 0 && l2 < LSEQ) {
            const f32x4* s4 = (const f32x4*)(x + ((size_t)(bb * LSEQ + l2)) * DIN + part * 8);
            f32x4 u0 = s4[0], u1 = s4[1];
            v[0] = f2bf(u0.x); v[1] = f2bf(u0.y); v[2] = f2bf(u0.z); v[3] = f2bf(u0.w);
            v[4] = f2bf(u1.x); v[5] = f2bf(u1.y); v[6] = f2bf(u1.z); v[7] = f2bf(u1.w);
        }
        *(short8*)&As[r][part * 8] = v;
    }
    __syncthreads();

    // ================= conv1: h1 rows m = 0..33 (h row = r0-1+m) =================
    f32x4 acc[2][4];     // full tiles: rows 0..31
    f32x4 acce[4];       // partial tile: rows 32..33 valid
    #pragma unroll
    for (int mt = 0; mt < 2; mt++)
        #pragma unroll
        for (int nt = 0; nt < 4; nt++)
            #pragma unroll
            for (int r = 0; r < 4; r++)
                acc[mt][nt][r] = 0.f;
    #pragma unroll
    for (int nt = 0; nt < 4; nt++)
        #pragma unroll
        for (int r = 0; r < 4; r++)
            acce[nt][r] = 0.f;

    {
        const short* bptr = Bt1 + (size_t)(wave * 64 + ml) * BK + q * 8;
        #pragma unroll 1
        for (int tap = 0; tap < 3; tap++) {
            int are = 32 + ml + tap; if (are > 35) are = 35;   // clamp; rows>1 of partial tile discarded
            #pragma unroll
            for (int cc = 0; cc < 8; cc++) {
                short8 af0 = *(const short8*)&As[ 0 + ml + tap][cc * 32 + q * 8];
                short8 af1 = *(const short8*)&As[16 + ml + tap][cc * 32 + q * 8];
                short8 af2 = *(const short8*)&As[are][cc * 32 + q * 8];
                short8 b0 = *(const short8*)(bptr + 0 * 16 * BK);
                short8 b1 = *(const short8*)(bptr + 1 * 16 * BK);
                short8 b2 = *(const short8*)(bptr + 2 * 16 * BK);
                short8 b3 = *(const short8*)(bptr + 3 * 16 * BK);
                bptr += FDIM * BK;
                acc[0][0] = __builtin_amdgcn_mfma_f32_16x16x32_bf16(af0, b0, acc[0][0], 0, 0, 0);
                acc[0][1] = __builtin_amdgcn_mfma_f32_16x16x32_bf16(af0, b1, acc[0][1], 0, 0, 0);
                acc[0][2] = __builtin_amdgcn_mfma_f32_16x16x32_bf16(af0, b2, acc[0][2], 0, 0, 0);
                acc[0][3] = __builtin_amdgcn_mfma_f32_16x16x32_bf16(af0, b3, acc[0][3], 0, 0, 0);
                acc[1][0] = __builtin_amdgcn_mfma_f32_16x16x32_bf16(af1, b0, acc[1][0], 0, 0, 0);
                acc[1][1] = __builtin_amdgcn_mfma_f32_16x16x32_bf16(af1, b1, acc[1][1], 0, 0, 0);
                acc[1][2] = __builtin_amdgcn_mfma_f32_16x16x32_bf16(af1, b2, acc[1][2], 0, 0, 0);
                acc[1][3] = __builtin_amdgcn_mfma_f32_16x16x32_bf16(af1, b3, acc[1][3], 0, 0, 0);
                acce[0]   = __builtin_amdgcn_mfma_f32_16x16x32_bf16(af2, b0, acce[0], 0, 0, 0);
                acce[1]   = __builtin_amdgcn_mfma_f32_16x16x32_bf16(af2, b1, acce[1], 0, 0, 0);
                acce[2]   = __builtin_amdgcn_mfma_f32_16x16x32_bf16(af2, b2, acce[2], 0, 0, 0);
                acce[3]   = __builtin_amdgcn_mfma_f32_16x16x32_bf16(af2, b3, acce[3], 0, 0, 0);
            }
        }
    }

    // ---- bias + LN1 reduction over 34 rows ----
    float cbv[4], gv[4], bv[4];
    #pragma unroll
    for (int nt = 0; nt < 4; nt++) {
        const int col = wave * 64 + nt * 16 + ml;
        cbv[nt] = c1b[col]; gv[nt] = g1v[col]; bv[nt] = b1v[col];
    }
    #pragma unroll
    for (int mt = 0; mt < 2; mt++)
        #pragma unroll
        for (int nt = 0; nt < 4; nt++)
            #pragma unroll
            for (int r = 0; r < 4; r++)
                acc[mt][nt][r] += cbv[nt];
    #pragma unroll
    for (int nt = 0; nt < 4; nt++)
        #pragma unroll
        for (int r = 0; r < 4; r++)
            acce[nt][r] += cbv[nt];

    #pragma unroll
    for (int mt = 0; mt < 2; mt++)
        #pragma unroll
        for (int r = 0; r < 4; r++) {
            float ps = 0.f, pq = 0.f;
            #pragma unroll
            for (int nt = 0; nt < 4; nt++) { float v = acc[mt][nt][r]; ps += v; pq += v * v; }
            #pragma unroll
            for (int d = 1; d < 16; d <<= 1) { ps += __shfl_xor(ps, d); pq += __shfl_xor(pq, d); }
            if (ml == 0) { const int row = mt * 16 + q * 4 + r; redS[row][wave] = ps; redQ[row][wave] = pq; }
        }
    #pragma unroll
    for (int r = 0; r < 2; r++) {          // partial tile rows 32,33 (q==0)
        float ps = 0.f, pq = 0.f;
        #pragma unroll
        for (int nt = 0; nt < 4; nt++) { float v = acce[nt][r]; ps += v; pq += v * v; }
        #pragma unroll
        for (int d = 1; d < 16; d <<= 1) { ps += __shfl_xor(ps, d); pq += __shfl_xor(pq, d); }
        if (ml == 0 && q == 0) { redS[32 + r][wave] = ps; redQ[32 + r][wave] = pq; }
    }
    __syncthreads();
    if (tid < 34) {
        float S = 0.f, Q = 0.f;
        #pragma unroll
        for (int w = 0; w < 4; w++) { S += redS[tid][w]; Q += redQ[tid][w]; }
        const float mu  = S * (1.f / 256.f);
        const float var = Q * (1.f / 256.f) - mu * mu;
        muS[tid] = mu; rsS[tid] = rsqrtf(var + 1e-5f);
    }
    __syncthreads();

    // ---- apply LN1+ReLU, write bf16 h1 tile (zero outside-batch rows) ----
    #pragma unroll
    for (int mt = 0; mt < 2; mt++)
        #pragma unroll
        for (int r = 0; r < 4; r++) {
            const int row = mt * 16 + q * 4 + r;
            const bool ok = (unsigned)(r0b - 1 + row) < (unsigned)LSEQ;
            const float mu = muS[row], rs = rsS[row];
            #pragma unroll
            for (int nt = 0; nt < 4; nt++) {
                const int col = wave * 64 + nt * 16 + ml;
                float v = (acc[mt][nt][r] - mu) * rs * gv[nt] + bv[nt];
                v = ok ? fmaxf(v, 0.f) : 0.f;
                Hs[row][col] = f2bf(v);
            }
        }
    if (q == 0) {
        #pragma unroll
        for (int r = 0; r < 2; r++) {
            const int row = 32 + r;
            const bool ok = (unsigned)(r0b - 1 + row) < (unsigned)LSEQ;
            const float mu = muS[row], rs = rsS[row];
            #pragma unroll
            for (int nt = 0; nt < 4; nt++) {
                const int col = wave * 64 + nt * 16 + ml;
                float v = (acce[nt][r] - mu) * rs * gv[nt] + bv[nt];
                v = ok ? fmaxf(v, 0.f) : 0.f;
                Hs[row][col] = f2bf(v);
            }
        }
    }
    __syncthreads();

    // ================= conv2: output rows 0..31 from Hs =================
    f32x4 acc2[2][4];
    #pragma unroll
    for (int mt = 0; mt < 2; mt++)
        #pragma unroll
        for (int nt = 0; nt < 4; nt++)
            #pragma unroll
            for (int r = 0; r < 4; r++)
                acc2[mt][nt][r] = 0.f;
    {
        const short* bptr = Bt2 + (size_t)(wave * 64 + ml) * BK + q * 8;
        #pragma unroll 1
        for (int tap = 0; tap < 3; tap++) {
            #pragma unroll
            for (int cc = 0; cc < 8; cc++) {
                short8 af0 = *(const short8*)&Hs[ 0 + ml + tap][cc * 32 + q * 8];
                short8 af1 = *(const short8*)&Hs[16 + ml + tap][cc * 32 + q * 8];
                short8 b0 = *(const short8*)(bptr + 0 * 16 * BK);
                short8 b1 = *(const short8*)(bptr + 1 * 16 * BK);
                short8 b2 = *(const short8*)(bptr + 2 * 16 * BK);
                short8 b3 = *(const short8*)(bptr + 3 * 16 * BK);
                bptr += FDIM * BK;
                acc2[0][0] = __builtin_amdgcn_mfma_f32_16x16x32_bf16(af0, b0, acc2[0][0], 0, 0, 0);
                acc2[0][1] = __builtin_amdgcn_mfma_f32_16x16x32_bf16(af0, b1, acc2[0][1], 0, 0, 0);
                acc2[0][2] = __builtin_amdgcn_mfma_f32_16x16x32_bf16(af0, b2, acc2[0][2], 0, 0, 0);
                acc2[0][3] = __builtin_amdgcn_mfma_f32_16x16x32_bf16(af0, b3, acc2[0][3], 0, 0, 0);
                acc2[1][0] = __builtin_amdgcn_mfma_f32_16x16x32_bf16(af1, b0, acc2[1][0], 0, 0, 0);
                acc2[1][1] = __builtin_amdgcn_mfma_f32_16x16x32_bf16(af1, b1, acc2[1][1], 0, 0, 0);
                acc2[1][2] = __builtin_amdgcn_mfma_f32_16x16x32_bf16(af1, b2, acc2[1][2], 0, 0, 0);
                acc2[1][3] = __builtin_amdgcn_mfma_f32_16x16x32_bf16(af1, b3, acc2[1][3], 0, 0, 0);
            }
        }
    }

    // ---- bias + LN2 + ReLU + fused linear ----
    float lwv[4];
    #pragma unroll
    for (int nt = 0; nt < 4; nt++) {
        const int col = wave * 64 + nt * 16 + ml;
        cbv[nt] = c2b[col]; gv[nt] = g2v[col]; bv[nt] = b2v[col]; lwv[nt] = lw[col];
    }
    #pragma unroll
    for (int mt = 0; mt < 2; mt++)
        #pragma unroll
        for (int nt = 0; nt < 4; nt++)
            #pragma unroll
            for (int r = 0; r < 4; r++)
                acc2[mt][nt][r] += cbv[nt];

    #pragma unroll
    for (int mt = 0; mt < 2; mt++)
        #pragma unroll
        for (int r = 0; r < 4; r++) {
            float ps = 0.f, pq = 0.f;
            #pragma unroll
            for (int nt = 0; nt < 4; nt++) { float v = acc2[mt][nt][r]; ps += v; pq += v * v; }
            #pragma unroll
            for (int d = 1; d < 16; d <<= 1) { ps += __shfl_xor(ps, d); pq += __shfl_xor(pq, d); }
            if (ml == 0) { const int row = mt * 16 + q * 4 + r; redS[row][wave] = ps; redQ[row][wave] = pq; }
        }
    __syncthreads();
    if (tid < MT) {
        float S = 0.f, Q = 0.f;
        #pragma unroll
        for (int w = 0; w < 4; w++) { S += redS[tid][w]; Q += redQ[tid][w]; }
        const float mu  = S * (1.f / 256.f);
        const float var = Q * (1.f / 256.f) - mu * mu;
        muS[tid] = mu; rsS[tid] = rsqrtf(var + 1e-5f);
    }
    __syncthreads();

    #pragma unroll
    for (int mt = 0; mt < 2; mt++)
        #pragma unroll
        for (int r = 0; r < 4; r++) {
            const int row = mt * 16 + q * 4 + r;
            const float mu = muS[row], rs = rsS[row];
            float pd = 0.f;
            #pragma unroll
            for (int nt = 0; nt < 4; nt++) {
                float v = (acc2[mt][nt][r] - mu) * rs * gv[nt] + bv[nt];
                v = fmaxf(v, 0.f);
                pd += v * lwv[nt];
            }
            #pragma unroll
            for (int d = 1; d < 16; d <<= 1) pd += __shfl_xor(pd, d);
            if (ml == 0) redD[row][wave] = pd;
        }
    __syncthreads();
    if (tid < MT) {
        float Dv = 0.f;
        #pragma unroll
        for (int w = 0; w < 4; w++) Dv += redD[tid][w];
        Dout[row0 + tid] = fmaxf(Dv + lb[0], 0.f);
    }
}

extern "C" void kernel_launch(void* const* d_in, const int* in_sizes, int n_in,
                              void* d_out, int out_size, void* d_ws, size_t ws_size,
                              hipStream_t stream)
{
    const float* x   = (const float*)d_in[0];
    const int*   dur = (const int*)d_in[1];
    const float* c1w = (const float*)d_in[3];
    const float* c1b = (const float*)d_in[4];
    const float* g1  = (const float*)d_in[5];
    const float* b1  = (const float*)d_in[6];
    const float* c2w = (const float*)d_in[7];
    const float* c2b = (const float*)d_in[8];
    const float* g2  = (const float*)d_in[9];
    const float* b2  = (const float*)d_in[10];
    const float* lw  = (const float*)d_in[11];
    const float* lb  = (const float*)d_in[12];

    const int M = (out_size - BATCH * LSEQ) / (BATCH * DIN);   // 4096
    float* out     = (float*)d_out;
    float* dur_out = out + (size_t)BATCH * M * DIN;

    char* ws   = (char*)d_ws;
    int*  fidx = (int*)ws;                                      // 512 KB
    short* wt1 = (short*)(ws + (512 << 10));                    // 384 KB
    short* wt2 = (short*)(ws + (512 << 10) + (384 << 10));      // 384 KB

    const int NCONV = (BATCH * LSEQ) / MT;        // 512 conv blocks (dispatched first)
    const int NEXP  = (BATCH * M) / 16;           // 8192 expand blocks

    hipLaunchKernelGGL(prep_kernel, dim3(BATCH + (3 * DIN * FDIM) / 512), dim3(512), 0, stream,
                       dur, fidx, M, c1w, c2w, wt1, wt2);
    hipLaunchKernelGGL(mega_kernel, dim3(NCONV + NEXP), dim3(256), 0, stream,
                       x, wt1, wt2, c1b, g1, b1, c2b, g2, b2, lw, lb, dur_out,
                       (const f32x4*)x, fidx, (f32x4*)d_out, NCONV);
}